// Round 11
// baseline (1621.650 us; speedup 1.0000x reference)
//
#include <hip/hip_runtime.h>

// 3-layer LSTM, B=256, T=2048, H=32, in=64. fp32.
// 128 blocks x 512 threads (8 waves); each block processes TWO batch
// elements (2*bi, 2*bi+1). Producer/consumer pipeline by 16-step chunks.
// Recurrent waves interleave the two sequences' chains (independent
// dataflow fills each chain's latency stalls). h broadcast via LDS
// write + 8x ds_read_b128, hidden under the other chain's compute.
// SIMD load balance (w&3): S0:{rec0,f1a} S1:{rec1,f2a} S2:{rec2,f1b}
// S3:{f0,f2b}. h_seq never touches HBM.

typedef float v2f __attribute__((ext_vector_type(2)));

constexpr int T_SEQ  = 2048;
constexpr int CH     = 16;             // timesteps per chunk
constexpr int NCHUNK = T_SEQ / CH;     // 128
constexpr int NPHASE = NCHUNK + 5;     // pipeline depth 6

#define GLOAD_LDS16(gsrc, ldst)                                                              \
    __builtin_amdgcn_global_load_lds((const __attribute__((address_space(1))) void*)(gsrc), \
                                     (__attribute__((address_space(3))) void*)(ldst),        \
                                     16, 0, 0)
#define KEEPV(x) asm volatile("" : "+v"(x))

__device__ __forceinline__ float rcp_f(float x) { return __builtin_amdgcn_rcpf(x); }

// returns x[l] + x[l^32] for every lane, via one permlane32_swap (VALU).
__device__ __forceinline__ float swap_sum32(float x) {
#if __has_builtin(__builtin_amdgcn_permlane32_swap)
    auto r = __builtin_amdgcn_permlane32_swap(__float_as_uint(x), __float_as_uint(x),
                                              false, false);
    return __uint_as_float(r[0]) + __uint_as_float(r[1]);
#else
    return x + __shfl_xor(x, 32);
#endif
}

// One step of one chain. Lane l owns gate rows l (A) and l+64 (B):
// l<32 -> A=i(sig), B=g(tanh); l>=32 -> A=f(sig), B=o(sig via tanh half-arg).
// hv[8] = h(t-1) broadcast (VGPR, identical in all lanes).
__device__ __forceinline__ void rec_step(int l, v2f xgv,
    const v2f (&whA)[16], const v2f (&whB)[16],
    const float4 (&hv)[8], float& c, float& z,
    float mt, float ca, float cb)
{
    v2f aA0 = {xgv.x, 0.f}, aA1 = {0.f, 0.f};
    v2f aB0 = {xgv.y, 0.f}, aB1 = {0.f, 0.f};
#pragma unroll
    for (int i = 0; i < 8; ++i) {
        const v2f lo = {hv[i].x, hv[i].y}, hi = {hv[i].z, hv[i].w};
        aA0 = lo * whA[2*i]   + aA0;  aA1 = hi * whA[2*i+1] + aA1;
        aB0 = lo * whB[2*i]   + aB0;  aB1 = hi * whB[2*i+1] + aB1;
    }
    const float ga = (aA0.x + aA1.x) + (aA0.y + aA1.y);
    const float gb = (aB0.x + aB1.x) + (aB0.y + aB1.y);

    const float sA = rcp_f(1.0f + __expf(-ga));           // i | f
    const float eb = __expf(mt * gb);                     // mt = 2 (g) / 1 (o)
    const float tb = fmaf(-2.0f, rcp_f(eb + 1.0f), 1.0f);
    const float vB = fmaf(ca, tb, cb);                    // g | o

    const float p  = sA * ((l < 32) ? vB : c);            // i*g | f*c
    const float cn = swap_sum32(p);                       // c_new, all lanes
    const float ec = __expf(2.0f * cn);
    const float th = fmaf(-2.0f, rcp_f(ec + 1.0f), 1.0f); // tanh(c_new)
    z = vB * th;                                          // lanes>=32: h_new
    c = cn;
}

// One chunk of recurrence for BOTH sequences, interleaved.
// hb*[64]: bounce buffer; all lanes write slot l, h values live in 32..63.
template<bool RING>
__device__ __forceinline__ void rec_chunk2(int l,
    const v2f* __restrict__ xgA, const v2f* __restrict__ xgB,   // [CH][64]
    float* __restrict__ ringA, float* __restrict__ ringB,       // [CH][32]
    float* hbA, float* hbB,                                     // [64]
    const v2f (&whA)[16], const v2f (&whB)[16],
    float4 (&hvA)[8], float4 (&hvB)[8],
    float& cA, float& zA, float& cB, float& zB,
    float mt, float ca, float cb)
{
    v2f xa = xgA[l], xb = xgB[l];
#pragma unroll
    for (int tt = 0; tt < CH; ++tt) {
        // ---- chain A ----
        rec_step(l, xa, whA, whB, hvA, cA, zA, mt, ca, cb);
        hbA[l] = zA;                                       // ds_write_b32
        if constexpr (RING) { if (l >= 32) ringA[tt*32 + (l-32)] = zA; }
        {   const float4* h4 = reinterpret_cast<const float4*>(hbA + 32);
#pragma unroll
            for (int i = 0; i < 8; ++i) hvA[i] = h4[i];    // latency hides under chain B
        }
        if (tt + 1 < CH) xa = xgA[(tt+1)*64 + l];
        // ---- chain B ----
        rec_step(l, xb, whA, whB, hvB, cB, zB, mt, ca, cb);
        hbB[l] = zB;
        if constexpr (RING) { if (l >= 32) ringB[tt*32 + (l-32)] = zB; }
        {   const float4* h4 = reinterpret_cast<const float4*>(hbB + 32);
#pragma unroll
            for (int i = 0; i < 8; ++i) hvB[i] = h4[i];    // hides under next A-dot
        }
        if (tt + 1 < CH) xb = xgB[(tt+1)*64 + l];
    }
}

// feeder from 32-wide LDS h ring, half chunk [tt0, tt0+8)
__device__ __forceinline__ void feed_h_half(int l, const float* __restrict__ hr,
    v2f* __restrict__ xg_out, const v2f (&wA)[16], const v2f (&wB)[16],
    float bA, float bB, int tt0)
{
#pragma unroll
    for (int t = 0; t < CH/2; ++t) {
        const int tt = tt0 + t;
        const float4* h4 = reinterpret_cast<const float4*>(hr + tt * 32);
        v2f a0 = {bA, 0.f}, a1 = {0.f, 0.f}, b0 = {bB, 0.f}, b1 = {0.f, 0.f};
#pragma unroll
        for (int i = 0; i < 8; ++i) {
            const float4 v = h4[i];
            const v2f lo = {v.x, v.y}, hi = {v.z, v.w};
            a0 = lo * wA[2*i] + a0;  a1 = hi * wA[2*i+1] + a1;
            b0 = lo * wB[2*i] + b0;  b1 = hi * wB[2*i+1] + b1;
        }
        xg_out[tt * 64 + l] = (v2f){(a0.x + a1.x) + (a0.y + a1.y),
                                    (b0.x + b1.x) + (b0.y + b1.y)};
    }
}

// feeder layer 0 from staged x (64-wide rows), full chunk
__device__ __forceinline__ void feed0_chunk(int l, const float* __restrict__ xs,
    v2f* __restrict__ xg_out, const v2f (&wA)[32], const v2f (&wB)[32],
    float bA, float bB)
{
#pragma unroll
    for (int tt = 0; tt < CH; ++tt) {
        const float4* xt = reinterpret_cast<const float4*>(xs + tt * 64);
        v2f a0 = {bA, 0.f}, a1 = {0.f, 0.f}, b0 = {bB, 0.f}, b1 = {0.f, 0.f};
#pragma unroll
        for (int i = 0; i < 16; ++i) {
            const float4 v = xt[i];
            const v2f lo = {v.x, v.y}, hi = {v.z, v.w};
            a0 = lo * wA[2*i] + a0;  a1 = hi * wA[2*i+1] + a1;
            b0 = lo * wB[2*i] + b0;  b1 = hi * wB[2*i+1] + b1;
        }
        xg_out[tt * 64 + l] = (v2f){(a0.x + a1.x) + (a0.y + a1.y),
                                    (b0.x + b1.x) + (b0.y + b1.y)};
    }
}

__global__ __launch_bounds__(512, 1)
void lstm3_dual_kernel(const float* __restrict__ x,
    const float* __restrict__ W_ih0, const float* __restrict__ W_hh0, const float* __restrict__ b0,
    const float* __restrict__ W_ih1, const float* __restrict__ W_hh1, const float* __restrict__ b1,
    const float* __restrict__ W_ih2, const float* __restrict__ W_hh2, const float* __restrict__ b2,
    const float* __restrict__ W_out, const float* __restrict__ b_out,
    float* __restrict__ out)
{
    const int bi = blockIdx.x;             // sequence pair (2bi, 2bi+1)
    const int w  = threadIdx.x >> 6;
    const int l  = threadIdx.x & 63;

    __shared__ v2f   xg[3][2][2][CH][64];      // [layer][seq][buf] 96 KB
    __shared__ float ring[2][2][2][CH][32];    // [lay01][seq][buf] 16 KB
    __shared__ float xstage[2][2][CH * 64];    // [seq][buf] 16 KB
    __shared__ float hbuf[3][2][64];           // [layer][seq] 1.5 KB

    if (w == 0 || w == 1 || w == 2) {      // ---- rec L (chunk p-(2L+1)) ----
        const int L = w;
        __builtin_amdgcn_s_setprio(1);
        const float* Whh = (L == 0) ? W_hh0 : (L == 1) ? W_hh1 : W_hh2;
        v2f whA[16], whB[16];
        const v2f* hA = reinterpret_cast<const v2f*>(Whh + l * 32);
        const v2f* hB = reinterpret_cast<const v2f*>(Whh + (l + 64) * 32);
#pragma unroll
        for (int i = 0; i < 16; ++i) { whA[i] = hA[i]; KEEPV(whA[i]); whB[i] = hB[i]; KEEPV(whB[i]); }
        const float mt = (l < 32) ? 2.f : 1.f;
        const float ca = (l < 32) ? 1.f : 0.5f;
        const float cb = (l < 32) ? 0.f : 0.5f;
        const float woutv = W_out[l & 31];
        float4 hvA[8], hvB[8];
#pragma unroll
        for (int i = 0; i < 8; ++i) { hvA[i] = make_float4(0.f,0.f,0.f,0.f); hvB[i] = hvA[i]; }
        float cA = 0.f, zA = 0.f, cB = 0.f, zB = 0.f;
        const int skew = 2 * L + 1;
        __syncthreads();
        for (int p = 0; p < NPHASE; ++p) {
            const int ci = p - skew;
            if (ci >= 0 && ci < NCHUNK) {
                if (L < 2)
                    rec_chunk2<true>(l, &xg[L][0][ci&1][0][0], &xg[L][1][ci&1][0][0],
                                     &ring[L][0][ci&1][0][0], &ring[L][1][ci&1][0][0],
                                     hbuf[L][0], hbuf[L][1],
                                     whA, whB, hvA, hvB, cA, zA, cB, zB, mt, ca, cb);
                else
                    rec_chunk2<false>(l, &xg[2][0][ci&1][0][0], &xg[2][1][ci&1][0][0],
                                      nullptr, nullptr,
                                      hbuf[2][0], hbuf[2][1],
                                      whA, whB, hvA, hvB, cA, zA, cB, zB, mt, ca, cb);
            }
            __syncthreads();
        }
        if (L == 2) {                       // projection for both sequences
            float s0 = (l >= 32) ? zA * woutv : 0.f;
            float s1 = (l >= 32) ? zB * woutv : 0.f;
#pragma unroll
            for (int off = 32; off; off >>= 1) { s0 += __shfl_xor(s0, off); s1 += __shfl_xor(s1, off); }
            if (l == 0) { out[2*bi] = s0 + b_out[0]; out[2*bi + 1] = s1 + b_out[0]; }
        }
    } else if (w == 3) {                   // ---- f0: xg0 from x, both seqs (chunk p) [SIMD3] ----
        v2f wA[32], wB[32];
        const v2f* pA = reinterpret_cast<const v2f*>(W_ih0 + l * 64);
        const v2f* pB = reinterpret_cast<const v2f*>(W_ih0 + (l + 64) * 64);
#pragma unroll
        for (int i = 0; i < 32; ++i) { wA[i] = pA[i]; KEEPV(wA[i]); wB[i] = pB[i]; KEEPV(wB[i]); }
        const float bAv = b0[l], bBv = b0[l + 64];
        const float* src0 = x + (size_t)(2*bi)     * T_SEQ * 64;
        const float* src1 = x + (size_t)(2*bi + 1) * T_SEQ * 64;
#pragma unroll
        for (int i = 0; i < 4; ++i) {
            GLOAD_LDS16(src0 + i*256 + l*4, &xstage[0][0][i*256 + l*4]);
            GLOAD_LDS16(src1 + i*256 + l*4, &xstage[1][0][i*256 + l*4]);
        }
        __syncthreads();                   // drains vmcnt -> chunk 0 resident
        for (int p = 0; p < NPHASE; ++p) {
            if (p + 1 < NCHUNK) {          // prefetch next chunk, both seqs
                const float* n0 = src0 + (size_t)(p + 1) * CH * 64;
                const float* n1 = src1 + (size_t)(p + 1) * CH * 64;
                float* d0 = &xstage[0][(p + 1) & 1][0];
                float* d1 = &xstage[1][(p + 1) & 1][0];
#pragma unroll
                for (int i = 0; i < 4; ++i) {
                    GLOAD_LDS16(n0 + i*256 + l*4, d0 + i*256 + l*4);
                    GLOAD_LDS16(n1 + i*256 + l*4, d1 + i*256 + l*4);
                }
            }
            if (p < NCHUNK) {
                feed0_chunk(l, xstage[0][p & 1], &xg[0][0][p & 1][0][0], wA, wB, bAv, bBv);
                feed0_chunk(l, xstage[1][p & 1], &xg[0][1][p & 1][0][0], wA, wB, bAv, bBv);
            }
            __syncthreads();
        }
    } else {                               // ---- feeder halves: w4=f1a w5=f2a w6=f1b w7=f2b ----
        const int fl  = (w == 4 || w == 6) ? 0 : 1;   // ring/layer index: 0->xg1, 1->xg2
        const int tt0 = (w <= 5) ? 0 : CH/2;
        const float* Wih = (fl == 0) ? W_ih1 : W_ih2;
        const float* bb  = (fl == 0) ? b1    : b2;
        const int skew   = (fl == 0) ? 2 : 4;
        v2f wA[16], wB[16];
        const v2f* pA = reinterpret_cast<const v2f*>(Wih + l * 32);
        const v2f* pB = reinterpret_cast<const v2f*>(Wih + (l + 64) * 32);
#pragma unroll
        for (int i = 0; i < 16; ++i) { wA[i] = pA[i]; KEEPV(wA[i]); wB[i] = pB[i]; KEEPV(wB[i]); }
        const float bAv = bb[l], bBv = bb[l + 64];
        __syncthreads();
        for (int p = 0; p < NPHASE; ++p) {
            const int ci = p - skew;
            if (ci >= 0 && ci < NCHUNK) {
                feed_h_half(l, &ring[fl][0][ci & 1][0][0], &xg[fl+1][0][ci & 1][0][0],
                            wA, wB, bAv, bBv, tt0);
                feed_h_half(l, &ring[fl][1][ci & 1][0][0], &xg[fl+1][1][ci & 1][0][0],
                            wA, wB, bAv, bBv, tt0);
            }
            __syncthreads();
        }
    }
}

extern "C" void kernel_launch(void* const* d_in, const int* in_sizes, int n_in,
                              void* d_out, int out_size, void* d_ws, size_t ws_size,
                              hipStream_t stream) {
    const float* x      = (const float*)d_in[0];
    const float* W_ih0  = (const float*)d_in[1];
    const float* W_hh0  = (const float*)d_in[2];
    const float* b0     = (const float*)d_in[3];
    const float* W_ih1  = (const float*)d_in[4];
    const float* W_hh1  = (const float*)d_in[5];
    const float* b1     = (const float*)d_in[6];
    const float* W_ih2  = (const float*)d_in[7];
    const float* W_hh2  = (const float*)d_in[8];
    const float* b2     = (const float*)d_in[9];
    const float* W_out  = (const float*)d_in[10];
    const float* b_out  = (const float*)d_in[11];

    lstm3_dual_kernel<<<128, 512, 0, stream>>>(x,
                                               W_ih0, W_hh0, b0,
                                               W_ih1, W_hh1, b1,
                                               W_ih2, W_hh2, b2,
                                               W_out, b_out,
                                               (float*)d_out);
}

// Round 12
// 1389.899 us; speedup vs baseline: 1.1667x; 1.1667x over previous
//
#include <hip/hip_runtime.h>

// 3-layer LSTM, B=256, T=2048, H=32, in=64. fp32.
// 128 blocks x 512 threads (8 waves); each block runs TWO sequences.
// Producer/consumer pipeline by 16-step chunks. Recurrent waves run both
// sequences' chains manually interleaved; the h broadcast is 32x v_readlane
// per chain (pure VALU - chains share NO memory counters, so chain B's
// instructions fill chain A's exp/rcp/readlane latency and vice versa).
// SIMDs: S0:{rec0,f1} S1:{rec1,f2} S2:{rec2} S3:{f0a,f0b}.
// h_seq never touches HBM.

typedef float v2f __attribute__((ext_vector_type(2)));

constexpr int T_SEQ  = 2048;
constexpr int CH     = 16;             // timesteps per chunk
constexpr int NCHUNK = T_SEQ / CH;     // 128
constexpr int NPHASE = NCHUNK + 5;     // pipeline depth 6

#define GLOAD_LDS16(gsrc, ldst)                                                              \
    __builtin_amdgcn_global_load_lds((const __attribute__((address_space(1))) void*)(gsrc), \
                                     (__attribute__((address_space(3))) void*)(ldst),        \
                                     16, 0, 0)
#define KEEPV(x) asm volatile("" : "+v"(x))

__device__ __forceinline__ float rcp_f(float x) { return __builtin_amdgcn_rcpf(x); }

// returns x[l] + x[l^32] for every lane, via one permlane32_swap (VALU).
__device__ __forceinline__ float swap_sum32(float x) {
#if __has_builtin(__builtin_amdgcn_permlane32_swap)
    auto r = __builtin_amdgcn_permlane32_swap(__float_as_uint(x), __float_as_uint(x),
                                              false, false);
    return __uint_as_float(r[0]) + __uint_as_float(r[1]);
#else
    return x + __shfl_xor(x, 32);
#endif
}

// One chunk of recurrence for BOTH sequences, chains interleaved.
// Lane l owns gate rows l (A) and l+64 (B): l<32 -> A=i(sig), B=g(tanh);
// l>=32 -> A=f(sig), B=o(sig via tanh half-arg).
// hsA/hsB: wave-uniform h per chain (SGPRs via readlane).
// zA/zB: lanes>=32 hold h_new after each step.
template<bool RING>
__device__ __forceinline__ void rec_chunk_dual(int l,
    const v2f* __restrict__ xgA, const v2f* __restrict__ xgB,   // [CH][64]
    float* __restrict__ ringA, float* __restrict__ ringB,       // [CH][32]
    const v2f (&whA)[16], const v2f (&whB)[16],
    float (&hsA)[32], float (&hsB)[32],
    float& cA, float& zA, float& cB, float& zB,
    float mt, float ca, float cb)
{
#pragma unroll
    for (int tt = 0; tt < CH; ++tt) {
        const v2f xa = xgA[tt * 64 + l];           // ds_read_b64, hoistable
        const v2f xb = xgB[tt * 64 + l];

        // ---- dual h-dot: 64 pk_fma, 8 independent chains ----
        v2f qA0 = {xa.x, 0.f}, qA1 = {0.f, 0.f}, qA2 = {xa.y, 0.f}, qA3 = {0.f, 0.f};
        v2f qB0 = {xb.x, 0.f}, qB1 = {0.f, 0.f}, qB2 = {xb.y, 0.f}, qB3 = {0.f, 0.f};
#pragma unroll
        for (int j = 0; j < 16; j += 2) {
            const v2f hA0 = {hsA[2*j],     hsA[2*j + 1]};
            const v2f hA1 = {hsA[2*j + 2], hsA[2*j + 3]};
            const v2f hB0 = {hsB[2*j],     hsB[2*j + 1]};
            const v2f hB1 = {hsB[2*j + 2], hsB[2*j + 3]};
            qA0 = hA0 * whA[j]     + qA0;  qA2 = hA0 * whB[j]     + qA2;
            qB0 = hB0 * whA[j]     + qB0;  qB2 = hB0 * whB[j]     + qB2;
            qA1 = hA1 * whA[j + 1] + qA1;  qA3 = hA1 * whB[j + 1] + qA3;
            qB1 = hB1 * whA[j + 1] + qB1;  qB3 = hB1 * whB[j + 1] + qB3;
        }
        const float gaA = (qA0.x + qA1.x) + (qA0.y + qA1.y);
        const float gbA = (qA2.x + qA3.x) + (qA2.y + qA3.y);
        const float gaB = (qB0.x + qB1.x) + (qB0.y + qB1.y);
        const float gbB = (qB2.x + qB3.x) + (qB2.y + qB3.y);

        // ---- dual activations (interleaved) ----
        const float sAA = rcp_f(1.0f + __expf(-gaA));
        const float sAB = rcp_f(1.0f + __expf(-gaB));
        const float ebA = __expf(mt * gbA);
        const float ebB = __expf(mt * gbB);
        const float tbA = fmaf(-2.0f, rcp_f(ebA + 1.0f), 1.0f);
        const float tbB = fmaf(-2.0f, rcp_f(ebB + 1.0f), 1.0f);
        const float vBA = fmaf(ca, tbA, cb);
        const float vBB = fmaf(ca, tbB, cb);

        const float pA = sAA * ((l < 32) ? vBA : cA);
        const float pB = sAB * ((l < 32) ? vBB : cB);
        const float cnA = swap_sum32(pA);
        const float cnB = swap_sum32(pB);
        const float ecA = __expf(2.0f * cnA);
        const float ecB = __expf(2.0f * cnB);
        const float thA = fmaf(-2.0f, rcp_f(ecA + 1.0f), 1.0f);
        const float thB = fmaf(-2.0f, rcp_f(ecB + 1.0f), 1.0f);
        zA = vBA * thA;  cA = cnA;
        zB = vBB * thB;  cB = cnB;

        if constexpr (RING) {
            if (l >= 32) {
                ringA[tt * 32 + (l - 32)] = zA;
                ringB[tt * 32 + (l - 32)] = zB;
            }
        }

        // ---- dual h broadcast: 64x readlane (pure VALU, interleaved) ----
        const int zbA = __float_as_int(zA), zbB = __float_as_int(zB);
#pragma unroll
        for (int k = 0; k < 32; ++k) {
            hsA[k] = __int_as_float(__builtin_amdgcn_readlane(zbA, k + 32));
            hsB[k] = __int_as_float(__builtin_amdgcn_readlane(zbB, k + 32));
        }
    }
}

// feeder from 32-wide LDS h ring, full chunk (one sequence)
__device__ __forceinline__ void feed_h_chunk(int l, const float* __restrict__ hr,
    v2f* __restrict__ xg_out, const v2f (&wA)[16], const v2f (&wB)[16],
    float bA, float bB)
{
#pragma unroll
    for (int tt = 0; tt < CH; ++tt) {
        const float4* h4 = reinterpret_cast<const float4*>(hr + tt * 32);
        v2f a0 = {bA, 0.f}, a1 = {0.f, 0.f}, b0 = {bB, 0.f}, b1 = {0.f, 0.f};
#pragma unroll
        for (int i = 0; i < 8; ++i) {
            const float4 v = h4[i];
            const v2f lo = {v.x, v.y}, hi = {v.z, v.w};
            a0 = lo * wA[2*i] + a0;  a1 = hi * wA[2*i+1] + a1;
            b0 = lo * wB[2*i] + b0;  b1 = hi * wB[2*i+1] + b1;
        }
        xg_out[tt * 64 + l] = (v2f){(a0.x + a1.x) + (a0.y + a1.y),
                                    (b0.x + b1.x) + (b0.y + b1.y)};
    }
}

// feeder layer 0 from staged x (64-wide rows), full chunk
__device__ __forceinline__ void feed0_chunk(int l, const float* __restrict__ xs,
    v2f* __restrict__ xg_out, const v2f (&wA)[32], const v2f (&wB)[32],
    float bA, float bB)
{
#pragma unroll
    for (int tt = 0; tt < CH; ++tt) {
        const float4* xt = reinterpret_cast<const float4*>(xs + tt * 64);
        v2f a0 = {bA, 0.f}, a1 = {0.f, 0.f}, b0 = {bB, 0.f}, b1 = {0.f, 0.f};
#pragma unroll
        for (int i = 0; i < 16; ++i) {
            const float4 v = xt[i];
            const v2f lo = {v.x, v.y}, hi = {v.z, v.w};
            a0 = lo * wA[2*i] + a0;  a1 = hi * wA[2*i+1] + a1;
            b0 = lo * wB[2*i] + b0;  b1 = hi * wB[2*i+1] + b1;
        }
        xg_out[tt * 64 + l] = (v2f){(a0.x + a1.x) + (a0.y + a1.y),
                                    (b0.x + b1.x) + (b0.y + b1.y)};
    }
}

__global__ __launch_bounds__(512, 1)
void lstm3_dual2_kernel(const float* __restrict__ x,
    const float* __restrict__ W_ih0, const float* __restrict__ W_hh0, const float* __restrict__ b0,
    const float* __restrict__ W_ih1, const float* __restrict__ W_hh1, const float* __restrict__ b1,
    const float* __restrict__ W_ih2, const float* __restrict__ W_hh2, const float* __restrict__ b2,
    const float* __restrict__ W_out, const float* __restrict__ b_out,
    float* __restrict__ out)
{
    const int bi = blockIdx.x;             // sequence pair (2bi, 2bi+1)
    const int w  = threadIdx.x >> 6;
    const int l  = threadIdx.x & 63;

    __shared__ v2f   xg[3][2][2][CH][64];      // [layer][seq][buf] 96 KB
    __shared__ float ring[2][2][2][CH][32];    // [lay01][seq][buf] 16 KB
    __shared__ float xstage[2][2][CH * 64];    // [seq][buf] 16 KB

    if (w < 3) {                           // ---- rec L, both seqs (chunk p-(2L+1)) ----
        const int L = w;
        __builtin_amdgcn_s_setprio(1);
        const float* Whh = (L == 0) ? W_hh0 : (L == 1) ? W_hh1 : W_hh2;
        v2f whA[16], whB[16];
        const v2f* hA = reinterpret_cast<const v2f*>(Whh + l * 32);
        const v2f* hB = reinterpret_cast<const v2f*>(Whh + (l + 64) * 32);
#pragma unroll
        for (int i = 0; i < 16; ++i) { whA[i] = hA[i]; KEEPV(whA[i]); whB[i] = hB[i]; KEEPV(whB[i]); }
        const float mt = (l < 32) ? 2.f : 1.f;
        const float ca = (l < 32) ? 1.f : 0.5f;
        const float cb = (l < 32) ? 0.f : 0.5f;
        const float woutv = W_out[l & 31];
        float hsA[32], hsB[32];
#pragma unroll
        for (int k = 0; k < 32; ++k) { hsA[k] = 0.f; hsB[k] = 0.f; }
        float cA = 0.f, zA = 0.f, cB = 0.f, zB = 0.f;
        const int skew = 2 * L + 1;
        __syncthreads();
        for (int p = 0; p < NPHASE; ++p) {
            const int ci = p - skew;
            if (ci >= 0 && ci < NCHUNK) {
                if (L < 2)
                    rec_chunk_dual<true>(l, &xg[L][0][ci&1][0][0], &xg[L][1][ci&1][0][0],
                                         &ring[L][0][ci&1][0][0], &ring[L][1][ci&1][0][0],
                                         whA, whB, hsA, hsB, cA, zA, cB, zB, mt, ca, cb);
                else
                    rec_chunk_dual<false>(l, &xg[2][0][ci&1][0][0], &xg[2][1][ci&1][0][0],
                                          nullptr, nullptr,
                                          whA, whB, hsA, hsB, cA, zA, cB, zB, mt, ca, cb);
            }
            __syncthreads();
        }
        if (L == 2) {                       // projection for both sequences
            float s0 = (l >= 32) ? zA * woutv : 0.f;
            float s1 = (l >= 32) ? zB * woutv : 0.f;
#pragma unroll
            for (int off = 32; off; off >>= 1) { s0 += __shfl_xor(s0, off); s1 += __shfl_xor(s1, off); }
            if (l == 0) { out[2*bi] = s0 + b_out[0]; out[2*bi + 1] = s1 + b_out[0]; }
        }
    } else if (w == 3 || w == 7) {         // ---- f0 seq s: xg0 from x (chunk p) [SIMD3] ----
        const int s = (w == 3) ? 0 : 1;
        v2f wA[32], wB[32];
        const v2f* pA = reinterpret_cast<const v2f*>(W_ih0 + l * 64);
        const v2f* pB = reinterpret_cast<const v2f*>(W_ih0 + (l + 64) * 64);
#pragma unroll
        for (int i = 0; i < 32; ++i) { wA[i] = pA[i]; KEEPV(wA[i]); wB[i] = pB[i]; KEEPV(wB[i]); }
        const float bAv = b0[l], bBv = b0[l + 64];
        const float* src = x + (size_t)(2*bi + s) * T_SEQ * 64;
#pragma unroll
        for (int i = 0; i < 4; ++i)
            GLOAD_LDS16(src + i*256 + l*4, &xstage[s][0][i*256 + l*4]);
        __syncthreads();                   // drains vmcnt -> chunk 0 resident
        for (int p = 0; p < NPHASE; ++p) {
            if (p + 1 < NCHUNK) {          // prefetch next chunk
                const float* ns = src + (size_t)(p + 1) * CH * 64;
                float* dst = &xstage[s][(p + 1) & 1][0];
#pragma unroll
                for (int i = 0; i < 4; ++i)
                    GLOAD_LDS16(ns + i*256 + l*4, dst + i*256 + l*4);
            }
            if (p < NCHUNK)
                feed0_chunk(l, xstage[s][p & 1], &xg[0][s][p & 1][0][0], wA, wB, bAv, bBv);
            __syncthreads();
        }
    } else if (w == 4 || w == 5) {         // ---- f1 / f2, both seqs [SIMD0/1] ----
        const int fl = (w == 4) ? 0 : 1;   // 0: h0r->xg1, 1: h1r->xg2
        const float* Wih = (fl == 0) ? W_ih1 : W_ih2;
        const float* bb  = (fl == 0) ? b1    : b2;
        const int skew   = (fl == 0) ? 2 : 4;
        v2f wA[16], wB[16];
        const v2f* pA = reinterpret_cast<const v2f*>(Wih + l * 32);
        const v2f* pB = reinterpret_cast<const v2f*>(Wih + (l + 64) * 32);
#pragma unroll
        for (int i = 0; i < 16; ++i) { wA[i] = pA[i]; KEEPV(wA[i]); wB[i] = pB[i]; KEEPV(wB[i]); }
        const float bAv = bb[l], bBv = bb[l + 64];
        __syncthreads();
        for (int p = 0; p < NPHASE; ++p) {
            const int ci = p - skew;
            if (ci >= 0 && ci < NCHUNK) {
                feed_h_chunk(l, &ring[fl][0][ci & 1][0][0], &xg[fl+1][0][ci & 1][0][0],
                             wA, wB, bAv, bBv);
                feed_h_chunk(l, &ring[fl][1][ci & 1][0][0], &xg[fl+1][1][ci & 1][0][0],
                             wA, wB, bAv, bBv);
            }
            __syncthreads();
        }
    } else {                               // ---- w6: barrier-idle [SIMD2] ----
        __syncthreads();
        for (int p = 0; p < NPHASE; ++p) __syncthreads();
    }
}

extern "C" void kernel_launch(void* const* d_in, const int* in_sizes, int n_in,
                              void* d_out, int out_size, void* d_ws, size_t ws_size,
                              hipStream_t stream) {
    const float* x      = (const float*)d_in[0];
    const float* W_ih0  = (const float*)d_in[1];
    const float* W_hh0  = (const float*)d_in[2];
    const float* b0     = (const float*)d_in[3];
    const float* W_ih1  = (const float*)d_in[4];
    const float* W_hh1  = (const float*)d_in[5];
    const float* b1     = (const float*)d_in[6];
    const float* W_ih2  = (const float*)d_in[7];
    const float* W_hh2  = (const float*)d_in[8];
    const float* b2     = (const float*)d_in[9];
    const float* W_out  = (const float*)d_in[10];
    const float* b_out  = (const float*)d_in[11];

    lstm3_dual2_kernel<<<128, 512, 0, stream>>>(x,
                                                W_ih0, W_hh0, b0,
                                                W_ih1, W_hh1, b1,
                                                W_ih2, W_hh2, b2,
                                                W_out, b_out,
                                                (float*)d_out);
}

// Round 13
// 692.662 us; speedup vs baseline: 2.3412x; 2.0066x over previous
//
#include <hip/hip_runtime.h>

// 3-layer LSTM, B=256, T=2048, H=32, in=64. fp32.
// 256 blocks x 384 threads (6 waves), producer/consumer pipeline by 16-step
// chunks (r9 structure). THE round-13 change: amdgpu_waves_per_eu(2,2)
// pins the compiler's occupancy target to the physical 2 waves/SIMD, raising
// the VGPR budget to 256 and stopping the allocator from spilling the
// weight arrays to scratch/AGPR (r6-r12 showed VGPR=80 vs ~120 needed ->
// per-step weight reloads on the serial recurrence chain).
//   w3: f0   xg0 = W_ih0@x + b0          (chunk p)      [SIMD3]
//   w0: rec0 layer-0 recurrence          (chunk p-1)    [SIMD0, + f1]
//   w4: f1   xg1 = W_ih1@h0 + b1         (chunk p-2)    [SIMD0]
//   w1: rec1 layer-1 recurrence          (chunk p-3)    [SIMD1, + f2]
//   w5: f2   xg2 = W_ih2@h1 + b2         (chunk p-4)    [SIMD1]
//   w2: rec2 layer-2 recurrence + proj   (chunk p-5)    [SIMD2]
// Rec step: 32 pk_fma (SGPR h via readlane) + rcp/exp acts + 1
// permlane32_swap gate exchange. h_seq never touches HBM.

typedef float v2f __attribute__((ext_vector_type(2)));

constexpr int T_SEQ  = 2048;
constexpr int CH     = 16;             // timesteps per chunk
constexpr int NCHUNK = T_SEQ / CH;     // 128
constexpr int NPHASE = NCHUNK + 5;     // pipeline depth 6

#define GLOAD_LDS16(gsrc, ldst)                                                              \
    __builtin_amdgcn_global_load_lds((const __attribute__((address_space(1))) void*)(gsrc), \
                                     (__attribute__((address_space(3))) void*)(ldst),        \
                                     16, 0, 0)
#define KEEPV(x) asm volatile("" : "+v"(x))

__device__ __forceinline__ float rcp_f(float x) { return __builtin_amdgcn_rcpf(x); }

// returns x[l] + x[l^32] for every lane, via one permlane32_swap (VALU).
__device__ __forceinline__ float swap_sum32(float x) {
#if __has_builtin(__builtin_amdgcn_permlane32_swap)
    auto r = __builtin_amdgcn_permlane32_swap(__float_as_uint(x), __float_as_uint(x),
                                              false, false);
    return __uint_as_float(r[0]) + __uint_as_float(r[1]);
#else
    return x + __shfl_xor(x, 32);
#endif
}

// One chunk of recurrence. Lane l owns gate rows l (A) and l+64 (B):
// l<32 -> A=i(sig), B=g(tanh); l>=32 -> A=f(sig), B=o(sig via tanh half-arg).
// hs[32]: wave-uniform h in SGPRs. z: lanes>=32 hold h_new after each step.
template<bool RING>
__device__ __forceinline__ void rec_chunk(int l,
    const v2f* __restrict__ xg_in,        // [CH][64] gate pre-activations
    float* __restrict__ ring_out,         // [CH][32] h chunk to next feeder
    const v2f (&whA)[16], const v2f (&whB)[16],
    float (&hs)[32], float& c, float& z,
    float mt, float ca, float cb)
{
    // prefetch the whole chunk's xg into registers (one lgkm batch)
    v2f xgr[CH];
#pragma unroll
    for (int tt = 0; tt < CH; ++tt) xgr[tt] = xg_in[tt * 64 + l];

#pragma unroll
    for (int tt = 0; tt < CH; ++tt) {
        // h-dot: 32 pk_fma with wave-uniform (SGPR) h operand, 4 chains
        v2f aA0 = {xgr[tt].x, 0.f}, aA1 = {0.f, 0.f};
        v2f aB0 = {xgr[tt].y, 0.f}, aB1 = {0.f, 0.f};
#pragma unroll
        for (int j = 0; j < 16; j += 2) {
            const v2f h0 = {hs[2*j],     hs[2*j + 1]};
            const v2f h1 = {hs[2*j + 2], hs[2*j + 3]};
            aA0 = h0 * whA[j]     + aA0;
            aB0 = h0 * whB[j]     + aB0;
            aA1 = h1 * whA[j + 1] + aA1;
            aB1 = h1 * whB[j + 1] + aB1;
        }
        const float ga = (aA0.x + aA1.x) + (aA0.y + aA1.y);
        const float gb = (aB0.x + aB1.x) + (aB0.y + aB1.y);

        const float sA = rcp_f(1.0f + __expf(-ga));           // i | f
        const float eb = __expf(mt * gb);                     // mt = 2 (g) / 1 (o)
        const float tb = fmaf(-2.0f, rcp_f(eb + 1.0f), 1.0f);
        const float vB = fmaf(ca, tb, cb);                    // g | o

        const float p  = sA * ((l < 32) ? vB : c);            // i*g | f*c
        const float cn = swap_sum32(p);                       // c_new, all lanes
        const float ec = __expf(2.0f * cn);
        const float th = fmaf(-2.0f, rcp_f(ec + 1.0f), 1.0f); // tanh(c_new)
        z = vB * th;                                          // lanes>=32: h_new
        c = cn;

        if constexpr (RING) { if (l >= 32) ring_out[tt * 32 + (l - 32)] = z; }

        // h broadcast: 32x readlane from lanes 32..63 -> SGPRs (no DS pipe)
        const int zb = __float_as_int(z);
#pragma unroll
        for (int k = 0; k < 32; ++k)
            hs[k] = __int_as_float(__builtin_amdgcn_readlane(zb, k + 32));
    }
}

// feeder from 32-wide LDS h ring
__device__ __forceinline__ void feed_h_chunk(int l, const float* __restrict__ hr,
    v2f* __restrict__ xg_out, const v2f (&wA)[16], const v2f (&wB)[16],
    float bA, float bB)
{
#pragma unroll
    for (int tt = 0; tt < CH; ++tt) {
        const float4* h4 = reinterpret_cast<const float4*>(hr + tt * 32);
        v2f a0 = {bA, 0.f}, a1 = {0.f, 0.f}, b0 = {bB, 0.f}, b1 = {0.f, 0.f};
#pragma unroll
        for (int i = 0; i < 8; ++i) {
            const float4 v = h4[i];
            const v2f lo = {v.x, v.y}, hi = {v.z, v.w};
            a0 = lo * wA[2*i] + a0;  a1 = hi * wA[2*i+1] + a1;
            b0 = lo * wB[2*i] + b0;  b1 = hi * wB[2*i+1] + b1;
        }
        xg_out[tt * 64 + l] = (v2f){(a0.x + a1.x) + (a0.y + a1.y),
                                    (b0.x + b1.x) + (b0.y + b1.y)};
    }
}

// feeder layer 0 from staged x (64-wide rows)
__device__ __forceinline__ void feed0_chunk(int l, const float* __restrict__ xs,
    v2f* __restrict__ xg_out, const v2f (&wA)[32], const v2f (&wB)[32],
    float bA, float bB)
{
#pragma unroll
    for (int tt = 0; tt < CH; ++tt) {
        const float4* xt = reinterpret_cast<const float4*>(xs + tt * 64);
        v2f a0 = {bA, 0.f}, a1 = {0.f, 0.f}, b0 = {bB, 0.f}, b1 = {0.f, 0.f};
#pragma unroll
        for (int i = 0; i < 16; ++i) {
            const float4 v = xt[i];
            const v2f lo = {v.x, v.y}, hi = {v.z, v.w};
            a0 = lo * wA[2*i] + a0;  a1 = hi * wA[2*i+1] + a1;
            b0 = lo * wB[2*i] + b0;  b1 = hi * wB[2*i+1] + b1;
        }
        xg_out[tt * 64 + l] = (v2f){(a0.x + a1.x) + (a0.y + a1.y),
                                    (b0.x + b1.x) + (b0.y + b1.y)};
    }
}

__global__ __launch_bounds__(384) __attribute__((amdgpu_waves_per_eu(2, 2)))
void lstm3_pin_kernel(const float* __restrict__ x,
    const float* __restrict__ W_ih0, const float* __restrict__ W_hh0, const float* __restrict__ b0,
    const float* __restrict__ W_ih1, const float* __restrict__ W_hh1, const float* __restrict__ b1,
    const float* __restrict__ W_ih2, const float* __restrict__ W_hh2, const float* __restrict__ b2,
    const float* __restrict__ W_out, const float* __restrict__ b_out,
    float* __restrict__ out)
{
    const int bi = blockIdx.x;
    const int w  = threadIdx.x >> 6;
    const int l  = threadIdx.x & 63;

    __shared__ v2f   xg0[2][CH][64];       // 16 KB
    __shared__ v2f   xg1[2][CH][64];       // 16 KB
    __shared__ v2f   xg2[2][CH][64];       // 16 KB
    __shared__ float h0r[2][CH][32];       // 4 KB
    __shared__ float h1r[2][CH][32];       // 4 KB
    __shared__ float xstage[2][CH * 64];   // 8 KB

    if (w == 0) {                          // ---- rec0 (chunk p-1) [SIMD0] ----
        __builtin_amdgcn_s_setprio(1);
        v2f whA[16], whB[16];
        const v2f* hA = reinterpret_cast<const v2f*>(W_hh0 + l * 32);
        const v2f* hB = reinterpret_cast<const v2f*>(W_hh0 + (l + 64) * 32);
#pragma unroll
        for (int i = 0; i < 16; ++i) { whA[i] = hA[i]; KEEPV(whA[i]); whB[i] = hB[i]; KEEPV(whB[i]); }
        const float mt = (l < 32) ? 2.f : 1.f;
        const float ca = (l < 32) ? 1.f : 0.5f;
        const float cb = (l < 32) ? 0.f : 0.5f;
        float hs[32];
#pragma unroll
        for (int k = 0; k < 32; ++k) hs[k] = 0.f;
        float c = 0.f, z = 0.f;
        __syncthreads();
        for (int p = 0; p < NPHASE; ++p) {
            const int ci = p - 1;
            if (ci >= 0 && ci < NCHUNK)
                rec_chunk<true>(l, &xg0[ci & 1][0][0], &h0r[ci & 1][0][0],
                                whA, whB, hs, c, z, mt, ca, cb);
            __syncthreads();
        }
    } else if (w == 1) {                   // ---- rec1 (chunk p-3) [SIMD1] ----
        __builtin_amdgcn_s_setprio(1);
        v2f whA[16], whB[16];
        const v2f* hA = reinterpret_cast<const v2f*>(W_hh1 + l * 32);
        const v2f* hB = reinterpret_cast<const v2f*>(W_hh1 + (l + 64) * 32);
#pragma unroll
        for (int i = 0; i < 16; ++i) { whA[i] = hA[i]; KEEPV(whA[i]); whB[i] = hB[i]; KEEPV(whB[i]); }
        const float mt = (l < 32) ? 2.f : 1.f;
        const float ca = (l < 32) ? 1.f : 0.5f;
        const float cb = (l < 32) ? 0.f : 0.5f;
        float hs[32];
#pragma unroll
        for (int k = 0; k < 32; ++k) hs[k] = 0.f;
        float c = 0.f, z = 0.f;
        __syncthreads();
        for (int p = 0; p < NPHASE; ++p) {
            const int ci = p - 3;
            if (ci >= 0 && ci < NCHUNK)
                rec_chunk<true>(l, &xg1[ci & 1][0][0], &h1r[ci & 1][0][0],
                                whA, whB, hs, c, z, mt, ca, cb);
            __syncthreads();
        }
    } else if (w == 2) {                   // ---- rec2 (chunk p-5) + proj [SIMD2] ----
        __builtin_amdgcn_s_setprio(1);
        v2f whA[16], whB[16];
        const v2f* hA = reinterpret_cast<const v2f*>(W_hh2 + l * 32);
        const v2f* hB = reinterpret_cast<const v2f*>(W_hh2 + (l + 64) * 32);
#pragma unroll
        for (int i = 0; i < 16; ++i) { whA[i] = hA[i]; KEEPV(whA[i]); whB[i] = hB[i]; KEEPV(whB[i]); }
        const float mt = (l < 32) ? 2.f : 1.f;
        const float ca = (l < 32) ? 1.f : 0.5f;
        const float cb = (l < 32) ? 0.f : 0.5f;
        const float woutv = W_out[l & 31];
        float hs[32];
#pragma unroll
        for (int k = 0; k < 32; ++k) hs[k] = 0.f;
        float c = 0.f, z = 0.f;
        __syncthreads();
        for (int p = 0; p < NPHASE; ++p) {
            const int ci = p - 5;
            if (ci >= 0 && ci < NCHUNK)
                rec_chunk<false>(l, &xg2[ci & 1][0][0], nullptr,
                                 whA, whB, hs, c, z, mt, ca, cb);
            __syncthreads();
        }
        // h2[T-1] lives in lanes 32..63 (unit u = l-32)
        float s = (l >= 32) ? z * woutv : 0.f;
#pragma unroll
        for (int off = 32; off; off >>= 1) s += __shfl_xor(s, off);
        if (l == 0) out[bi] = s + b_out[0];
    } else if (w == 3) {                   // ---- f0: xg0 from x (chunk p) [SIMD3] ----
        v2f wA[32], wB[32];
        const v2f* pA = reinterpret_cast<const v2f*>(W_ih0 + l * 64);
        const v2f* pB = reinterpret_cast<const v2f*>(W_ih0 + (l + 64) * 64);
#pragma unroll
        for (int i = 0; i < 32; ++i) { wA[i] = pA[i]; KEEPV(wA[i]); wB[i] = pB[i]; KEEPV(wB[i]); }
        const float bAv = b0[l], bBv = b0[l + 64];
        const float* src = x + (size_t)bi * T_SEQ * 64;
#pragma unroll
        for (int i = 0; i < 4; ++i)
            GLOAD_LDS16(src + i * 256 + l * 4, &xstage[0][i * 256 + l * 4]);
        __syncthreads();                   // drains vmcnt -> chunk 0 resident
        for (int p = 0; p < NPHASE; ++p) {
            if (p + 1 < NCHUNK) {          // prefetch next chunk
                const float* ns = src + (size_t)(p + 1) * CH * 64;
                float* dst = &xstage[(p + 1) & 1][0];
#pragma unroll
                for (int i = 0; i < 4; ++i)
                    GLOAD_LDS16(ns + i * 256 + l * 4, dst + i * 256 + l * 4);
            }
            if (p < NCHUNK)
                feed0_chunk(l, xstage[p & 1], &xg0[p & 1][0][0], wA, wB, bAv, bBv);
            __syncthreads();
        }
    } else if (w == 4) {                   // ---- f1: xg1 from h0 ring (chunk p-2) [SIMD0] ----
        v2f wA[16], wB[16];
        const v2f* pA = reinterpret_cast<const v2f*>(W_ih1 + l * 32);
        const v2f* pB = reinterpret_cast<const v2f*>(W_ih1 + (l + 64) * 32);
#pragma unroll
        for (int i = 0; i < 16; ++i) { wA[i] = pA[i]; KEEPV(wA[i]); wB[i] = pB[i]; KEEPV(wB[i]); }
        const float bAv = b1[l], bBv = b1[l + 64];
        __syncthreads();
        for (int p = 0; p < NPHASE; ++p) {
            const int ci = p - 2;
            if (ci >= 0 && ci < NCHUNK)
                feed_h_chunk(l, &h0r[ci & 1][0][0], &xg1[ci & 1][0][0], wA, wB, bAv, bBv);
            __syncthreads();
        }
    } else {                               // ---- f2: xg2 from h1 ring (chunk p-4) [SIMD1] ----
        v2f wA[16], wB[16];
        const v2f* pA = reinterpret_cast<const v2f*>(W_ih2 + l * 32);
        const v2f* pB = reinterpret_cast<const v2f*>(W_ih2 + (l + 64) * 32);
#pragma unroll
        for (int i = 0; i < 16; ++i) { wA[i] = pA[i]; KEEPV(wA[i]); wB[i] = pB[i]; KEEPV(wB[i]); }
        const float bAv = b2[l], bBv = b2[l + 64];
        __syncthreads();
        for (int p = 0; p < NPHASE; ++p) {
            const int ci = p - 4;
            if (ci >= 0 && ci < NCHUNK)
                feed_h_chunk(l, &h1r[ci & 1][0][0], &xg2[ci & 1][0][0], wA, wB, bAv, bBv);
            __syncthreads();
        }
    }
}

extern "C" void kernel_launch(void* const* d_in, const int* in_sizes, int n_in,
                              void* d_out, int out_size, void* d_ws, size_t ws_size,
                              hipStream_t stream) {
    const float* x      = (const float*)d_in[0];
    const float* W_ih0  = (const float*)d_in[1];
    const float* W_hh0  = (const float*)d_in[2];
    const float* b0     = (const float*)d_in[3];
    const float* W_ih1  = (const float*)d_in[4];
    const float* W_hh1  = (const float*)d_in[5];
    const float* b1     = (const float*)d_in[6];
    const float* W_ih2  = (const float*)d_in[7];
    const float* W_hh2  = (const float*)d_in[8];
    const float* b2     = (const float*)d_in[9];
    const float* W_out  = (const float*)d_in[10];
    const float* b_out  = (const float*)d_in[11];

    lstm3_pin_kernel<<<256, 384, 0, stream>>>(x,
                                              W_ih0, W_hh0, b0,
                                              W_ih1, W_hh1, b1,
                                              W_ih2, W_hh2, b2,
                                              W_out, b_out,
                                              (float*)d_out);
}